// Round 2
// baseline (1029.781 us; speedup 1.0000x reference)
//
#include <hip/hip_runtime.h>

#define N 16384
#define B 512
#define NNZ 131072
#define NITER 4          // R + 1
#define BLOCK 512
#define CPT (N / BLOCK)  // 32 columns per thread

// ---------- math helpers ----------
__device__ __forceinline__ float sigmoid_(float x) {
    return 1.f / (1.f + __expf(-x));
}
__device__ __forceinline__ float tanh_(float x) {
    // overflow-safe: exp(2x)->inf gives 1, exp(2x)->0 gives -1
    return 1.f - 2.f / (__expf(2.f * x) + 1.f);
}

// ---------- index dtype detection ----------
__global__ void detect_kernel(const int* __restrict__ w, int* __restrict__ flag) {
    if (blockIdx.x == 0 && threadIdx.x == 0) {
        int all0 = 1;
        for (int i = 1; i < 64; i += 2) all0 &= (w[i] == 0);
        *flag = all0;   // 1 => int64 layout, 0 => int32 layout
    }
}

__device__ __forceinline__ int dec_row(const int* w, int k, int is64) {
    return is64 ? w[4 * k]     : w[2 * k];
}
__device__ __forceinline__ int dec_col(const int* w, int k, int is64) {
    return is64 ? w[4 * k + 2] : w[2 * k + 1];
}

// ---------- CSC build ----------
__global__ void hist_kernel(const int* __restrict__ w, const int* __restrict__ flag,
                            int* __restrict__ counts) {
    int k = blockIdx.x * 256 + threadIdx.x;
    int is64 = *flag;
    int col = dec_col(w, k, is64);
    atomicAdd(&counts[col], 1);
}

// single block, 1024 threads, 16 elems each -> exclusive scan of 16384 counts
__global__ void scan_kernel(const int* __restrict__ counts, int* __restrict__ col_start) {
    __shared__ int sums[1024];
    int t = threadIdx.x;
    int base = t * 16;
    int local[16];
    int run = 0;
    for (int i = 0; i < 16; ++i) { local[i] = run; run += counts[base + i]; }
    sums[t] = run;
    __syncthreads();
    for (int off = 1; off < 1024; off <<= 1) {
        int v = (t >= off) ? sums[t - off] : 0;
        __syncthreads();
        sums[t] += v;
        __syncthreads();
    }
    int prev = (t == 0) ? 0 : sums[t - 1];
    for (int i = 0; i < 16; ++i) col_start[base + i] = prev + local[i];
    if (t == 1023) col_start[N] = prev + run;
}

__global__ void copy_cursor_kernel(const int* __restrict__ col_start, int* __restrict__ cursor) {
    int i = blockIdx.x * 256 + threadIdx.x;
    cursor[i] = col_start[i];
}

// entries[pos] = { row, float_bits(val) }, column-sorted
__global__ void scatter_kernel(const int* __restrict__ w, const float* __restrict__ kern,
                               const int* __restrict__ flag, int* __restrict__ cursor,
                               int2* __restrict__ entries) {
    int k = blockIdx.x * 256 + threadIdx.x;
    int is64 = *flag;
    int row = dec_row(w, k, is64);
    int col = dec_col(w, k, is64);
    int pos = atomicAdd(&cursor[col], 1);
    entries[pos] = make_int2(row, __float_as_int(kern[k]));
}

__global__ void pack_bias_kernel(const float* __restrict__ bi, const float* __restrict__ bf,
                                 const float* __restrict__ bo, const float* __restrict__ bg,
                                 float4* __restrict__ b4) {
    int i = blockIdx.x * 256 + threadIdx.x;
    b4[i] = make_float4(bi[i], bf[i], bo[i], bg[i]);
}

// ---------- fully fused: one workgroup per batch element, h resident in LDS ----------
__global__ __launch_bounds__(BLOCK, 4) void lstm_fused_kernel(
        const float*  __restrict__ x,          // (B, N) row-major
        float*        __restrict__ out,        // (B, N) row-major
        const int*    __restrict__ col_start,  // N+1
        const int2*   __restrict__ entries,    // NNZ, column-sorted (row, val)
        const float4* __restrict__ b4) {       // N  (bi, bf, bo, bg)
    __shared__ float h[N];   // 64 KB: this batch element's full hidden state
    int b = blockIdx.x;
    int t = threadIdx.x;

    // load x[b, :] into LDS (coalesced float4)
    const float4* xr = (const float4*)(x + (size_t)b * N);
    float4* h4 = (float4*)h;
    for (int i = t; i < N / 4; i += BLOCK) h4[i] = xr[i];

    float cc[CPT];
    #pragma unroll
    for (int i = 0; i < CPT; ++i) cc[i] = 0.f;

    for (int it = 0; it < NITER; ++it) {
        __syncthreads();   // h (or x) fully written before gathers
        float zz[CPT];
        #pragma unroll
        for (int i = 0; i < CPT; ++i) {
            int col = t + i * BLOCK;
            int s = col_start[col];
            int e = col_start[col + 1];
            float z = 0.f;
            for (int k = s; k < e; ++k) {
                int2 en = entries[k];
                z = fmaf(__int_as_float(en.y), h[en.x], z);
            }
            zz[i] = z;
        }
        __syncthreads();   // all z computed before h is overwritten
        #pragma unroll
        for (int i = 0; i < CPT; ++i) {
            int col = t + i * BLOCK;
            float4 bb = b4[col];
            float z = zz[i];
            float ig = sigmoid_(z + bb.x);
            float fg = sigmoid_(z + bb.y);
            float og = sigmoid_(z + bb.z);
            float gg = tanh_(z + bb.w);
            float c = fg * cc[i] + ig * gg;
            cc[i] = c;
            h[col] = og * tanh_(c);
        }
    }
    __syncthreads();
    // h[:, b] == out[b, :] — contiguous, coalesced write, no transpose needed
    float4* orow = (float4*)(out + (size_t)b * N);
    for (int i = t; i < N / 4; i += BLOCK) orow[i] = h4[i];
}

extern "C" void kernel_launch(void* const* d_in, const int* in_sizes, int n_in,
                              void* d_out, int out_size, void* d_ws, size_t ws_size,
                              hipStream_t stream) {
    const float* x    = (const float*)d_in[0];
    const float* kern = (const float*)d_in[1];
    const float* b_i  = (const float*)d_in[2];
    const float* b_f  = (const float*)d_in[3];
    const float* b_o  = (const float*)d_in[4];
    const float* b_g  = (const float*)d_in[5];
    const int*   idxw = (const int*)d_in[6];

    char* ws = (char*)d_ws;
    int2*   entries   = (int2*)  (ws + 0);         // 1048576 B
    float4* b4        = (float4*)(ws + 1048576);   // 262144 B
    int*    col_start = (int*)   (ws + 1310720);   // (N+1)*4
    int*    cursor    = (int*)   (ws + 1376512);   // N*4
    int*    counts    = (int*)   (ws + 1442048);   // N*4
    int*    flag      = (int*)   (ws + 1507584);   // 4

    hipMemsetAsync(counts, 0, N * sizeof(int), stream);

    detect_kernel<<<1, 64, 0, stream>>>(idxw, flag);
    hist_kernel<<<NNZ / 256, 256, 0, stream>>>(idxw, flag, counts);
    scan_kernel<<<1, 1024, 0, stream>>>(counts, col_start);
    copy_cursor_kernel<<<N / 256, 256, 0, stream>>>(col_start, cursor);
    scatter_kernel<<<NNZ / 256, 256, 0, stream>>>(idxw, kern, flag, cursor, entries);
    pack_bias_kernel<<<N / 256, 256, 0, stream>>>(b_i, b_f, b_o, b_g, b4);

    lstm_fused_kernel<<<B, BLOCK, 0, stream>>>(x, (float*)d_out, col_start, entries, b4);
}

// Round 4
// 312.517 us; speedup vs baseline: 3.2951x; 3.2951x over previous
//
#include <hip/hip_runtime.h>
#include <hip/hip_fp16.h>

#define N 16384
#define B 512
#define NNZ 131072

// ---------- math helpers ----------
__device__ __forceinline__ float sigmoid_(float x) {
    return 1.f / (1.f + __expf(-x));
}
__device__ __forceinline__ float tanh_(float x) {
    // overflow-safe: exp(2x)->inf gives 1, exp(2x)->0 gives -1
    return 1.f - 2.f / (__expf(2.f * x) + 1.f);
}

// ---------- inline index dtype detection ----------
// int64 little-endian with values < 16384 => every odd 32-bit word is zero.
__device__ __forceinline__ int is64_(const int* __restrict__ w) {
    int a = 1;
    #pragma unroll
    for (int i = 1; i < 16; i += 2) a &= (w[i] == 0);
    return a;
}

// ---------- CSC build ----------
__global__ void hist_kernel(const int* __restrict__ w, int* __restrict__ counts) {
    int k = blockIdx.x * 256 + threadIdx.x;
    int is64 = is64_(w);
    int col = is64 ? w[4 * k + 2] : w[2 * k + 1];
    atomicAdd(&counts[col], 1);
}

// single block, 1024 threads, 16 elems each -> exclusive scan of 16384 counts.
// writes BOTH col_start and the scatter cursor copy.
__global__ void scan_kernel(const int* __restrict__ counts, int* __restrict__ col_start,
                            int* __restrict__ cursor) {
    __shared__ int sums[1024];
    int t = threadIdx.x;
    int base = t * 16;
    int local[16];
    int run = 0;
    for (int i = 0; i < 16; ++i) { local[i] = run; run += counts[base + i]; }
    sums[t] = run;
    __syncthreads();
    for (int off = 1; off < 1024; off <<= 1) {
        int v = (t >= off) ? sums[t - off] : 0;
        __syncthreads();
        sums[t] += v;
        __syncthreads();
    }
    int prev = (t == 0) ? 0 : sums[t - 1];
    for (int i = 0; i < 16; ++i) {
        col_start[base + i] = prev + local[i];
        cursor[base + i]    = prev + local[i];
    }
    if (t == 1023) col_start[N] = prev + run;
}

// entries[pos] = { row, float_bits(val) }, column-sorted
__global__ void scatter_kernel(const int* __restrict__ w, const float* __restrict__ kern,
                               int* __restrict__ cursor, int2* __restrict__ entries) {
    int k = blockIdx.x * 256 + threadIdx.x;
    int is64 = is64_(w);
    int row = is64 ? w[4 * k]     : w[2 * k];
    int col = is64 ? w[4 * k + 2] : w[2 * k + 1];
    int pos = atomicAdd(&cursor[col], 1);
    entries[pos] = make_int2(row, __float_as_int(kern[k]));
}

__global__ void pack_bias_kernel(const float* __restrict__ bi, const float* __restrict__ bf,
                                 const float* __restrict__ bo, const float* __restrict__ bg,
                                 float4* __restrict__ b4) {
    int i = blockIdx.x * 256 + threadIdx.x;
    b4[i] = make_float4(bi[i], bf[i], bo[i], bg[i]);
}

// ---------- transposes with dtype conversion ----------
// in: rows x cols f32  ->  out: cols x rows f16
__global__ void transpose_f32_f16_kernel(const float* __restrict__ in, __half* __restrict__ out,
                                         int rows, int cols) {
    __shared__ float tile[32][33];
    int bx = blockIdx.x * 32, by = blockIdx.y * 32;
    int tx = threadIdx.x, ty = threadIdx.y;   // 32 x 8
    for (int i = 0; i < 32; i += 8)
        tile[ty + i][tx] = in[(size_t)(by + ty + i) * cols + (bx + tx)];
    __syncthreads();
    for (int i = 0; i < 32; i += 8)
        out[(size_t)(bx + ty + i) * rows + (by + tx)] = __float2half(tile[tx][ty + i]);
}

// in: rows x cols f16  ->  out: cols x rows f32
__global__ void transpose_f16_f32_kernel(const __half* __restrict__ in, float* __restrict__ out,
                                         int rows, int cols) {
    __shared__ float tile[32][33];
    int bx = blockIdx.x * 32, by = blockIdx.y * 32;
    int tx = threadIdx.x, ty = threadIdx.y;
    for (int i = 0; i < 32; i += 8)
        tile[ty + i][tx] = __half2float(in[(size_t)(by + ty + i) * cols + (bx + tx)]);
    __syncthreads();
    for (int i = 0; i < 32; i += 8)
        out[(size_t)(bx + ty + i) * rows + (by + tx)] = tile[tx][ty + i];
}

// ---------- fused spmm + LSTM gates, one block per output column ----------
// 256 threads = 512 batch lanes as half2. Entry reads are block-uniform ->
// scalar loads; h-row gathers are 1 KB contiguous per entry (fully coalesced).
// FIRST: c==0, skip c read. LAST: c dead after, skip c write.
template <bool FIRST, bool LAST>
__global__ __launch_bounds__(256) void lstm_iter_kernel(
        const __half2* __restrict__ hin,     // (N, B/2)
        __half2*       __restrict__ hout,    // (N, B/2)
        float2*        __restrict__ c,       // (N, B/2) fp32 pairs
        const int*     __restrict__ col_start,
        const int2*    __restrict__ entries,
        const float4*  __restrict__ b4) {
    int col = blockIdx.x;
    int t = threadIdx.x;
    int s = col_start[col];
    int e = col_start[col + 1];

    float zx = 0.f, zy = 0.f;
    for (int k = s; k < e; ++k) {
        int2 en = entries[k];
        float v = __int_as_float(en.y);
        __half2 hv = hin[(size_t)en.x * (B / 2) + t];
        float2 hf = __half22float2(hv);
        zx = fmaf(v, hf.x, zx);
        zy = fmaf(v, hf.y, zy);
    }

    float4 bb = b4[col];
    size_t idx = (size_t)col * (B / 2) + t;
    float2 cv = FIRST ? make_float2(0.f, 0.f) : c[idx];

    float i0 = sigmoid_(zx + bb.x), f0 = sigmoid_(zx + bb.y);
    float o0 = sigmoid_(zx + bb.z), g0 = tanh_(zx + bb.w);
    float cx = f0 * cv.x + i0 * g0;
    float hx = o0 * tanh_(cx);

    float i1 = sigmoid_(zy + bb.x), f1 = sigmoid_(zy + bb.y);
    float o1 = sigmoid_(zy + bb.z), g1 = tanh_(zy + bb.w);
    float cy = f1 * cv.y + i1 * g1;
    float hy = o1 * tanh_(cy);

    if (!LAST) c[idx] = make_float2(cx, cy);
    hout[idx] = __halves2half2(__float2half_rn(hx), __float2half_rn(hy));
}

extern "C" void kernel_launch(void* const* d_in, const int* in_sizes, int n_in,
                              void* d_out, int out_size, void* d_ws, size_t ws_size,
                              hipStream_t stream) {
    const float* x    = (const float*)d_in[0];
    const float* kern = (const float*)d_in[1];
    const float* b_i  = (const float*)d_in[2];
    const float* b_f  = (const float*)d_in[3];
    const float* b_o  = (const float*)d_in[4];
    const float* b_g  = (const float*)d_in[5];
    const int*   idxw = (const int*)d_in[6];

    char* ws = (char*)d_ws;
    __half2* hA        = (__half2*)(ws + 0);          // 16777216 B
    __half2* hB        = (__half2*)(ws + 16777216);   // 16777216 B
    float2*  c         = (float2*) (ws + 33554432);   // 33554432 B
    int2*    entries   = (int2*)   (ws + 67108864);   // 1048576 B
    float4*  b4        = (float4*) (ws + 68157440);   // 262144 B
    int*     col_start = (int*)    (ws + 68419584);   // 66560 B (padded)
    int*     cursor    = (int*)    (ws + 68486144);   // 65536 B
    int*     counts    = (int*)    (ws + 68551680);   // 65536 B

    hipMemsetAsync(counts, 0, N * sizeof(int), stream);

    hist_kernel<<<NNZ / 256, 256, 0, stream>>>(idxw, counts);
    scan_kernel<<<1, 1024, 0, stream>>>(counts, col_start, cursor);
    scatter_kernel<<<NNZ / 256, 256, 0, stream>>>(idxw, kern, cursor, entries);
    pack_bias_kernel<<<N / 256, 256, 0, stream>>>(b_i, b_f, b_o, b_g, b4);

    // xT : (B,N) f32 -> (N,B) f16 into hA
    transpose_f32_f16_kernel<<<dim3(N / 32, B / 32), dim3(32, 8), 0, stream>>>(
        x, (__half*)hA, B, N);

    // 4 iterations, ping-pong hA <-> hB; c in fp32 ws (skipped read on first,
    // skipped write on last).
    lstm_iter_kernel<true,  false><<<N, 256, 0, stream>>>(hA, hB, c, col_start, entries, b4);
    lstm_iter_kernel<false, false><<<N, 256, 0, stream>>>(hB, hA, c, col_start, entries, b4);
    lstm_iter_kernel<false, false><<<N, 256, 0, stream>>>(hA, hB, c, col_start, entries, b4);
    lstm_iter_kernel<false, true ><<<N, 256, 0, stream>>>(hB, hA, c, col_start, entries, b4);

    // final h in hA: (N,B) f16 -> (B,N) f32 into d_out
    transpose_f16_f32_kernel<<<dim3(B / 32, N / 32), dim3(32, 8), 0, stream>>>(
        (const __half*)hA, (float*)d_out, N, B);
}

// Round 5
// 256.700 us; speedup vs baseline: 4.0116x; 1.2174x over previous
//
#include <hip/hip_runtime.h>
#include <hip/hip_fp16.h>

#define N 16384
#define B 512
#define NNZ 131072
#define KMAX 16          // ELL width; Poisson(8) tail spills to overflow list

// ---------- math helpers ----------
__device__ __forceinline__ float sigmoid_(float x) {
    return 1.f / (1.f + __expf(-x));
}
__device__ __forceinline__ float tanh_(float x) {
    // overflow-safe: exp(2x)->inf gives 1, exp(2x)->0 gives -1
    return 1.f - 2.f / (__expf(2.f * x) + 1.f);
}

// ---------- inline index dtype detection ----------
// int64 little-endian with values < 16384 => every odd 32-bit word is zero.
__device__ __forceinline__ int is64_(const int* __restrict__ w) {
    int a = 1;
    #pragma unroll
    for (int i = 1; i < 16; i += 2) a &= (w[i] == 0);
    return a;
}

// ---------- one-shot ELL build ----------
// ell[col*KMAX + slot] = (u16 row) | (f16 val << 16); overflow -> (col, packed) list.
__global__ void fill_ell_kernel(const int* __restrict__ w, const float* __restrict__ kern,
                                int* __restrict__ counts, unsigned int* __restrict__ ell,
                                uint2* __restrict__ ovf, int* __restrict__ ovf_cnt) {
    int k = blockIdx.x * 256 + threadIdx.x;
    int is64 = is64_(w);
    int row = is64 ? w[4 * k]     : w[2 * k];
    int col = is64 ? w[4 * k + 2] : w[2 * k + 1];
    unsigned int packed = (unsigned int)(unsigned short)row |
                          ((unsigned int)__half_as_ushort(__float2half_rn(kern[k])) << 16);
    int slot = atomicAdd(&counts[col], 1);
    if (slot < KMAX) {
        ell[col * KMAX + slot] = packed;
    } else {
        int pos = atomicAdd(ovf_cnt, 1);
        ovf[pos] = make_uint2((unsigned int)col, packed);
    }
}

__global__ void pack_bias_kernel(const float* __restrict__ bi, const float* __restrict__ bf,
                                 const float* __restrict__ bo, const float* __restrict__ bg,
                                 float4* __restrict__ b4) {
    int i = blockIdx.x * 256 + threadIdx.x;
    b4[i] = make_float4(bi[i], bf[i], bo[i], bg[i]);
}

// ---------- transposes with dtype conversion ----------
// in: rows x cols f32  ->  out: cols x rows f16
__global__ void transpose_f32_f16_kernel(const float* __restrict__ in, __half* __restrict__ out,
                                         int rows, int cols) {
    __shared__ float tile[32][33];
    int bx = blockIdx.x * 32, by = blockIdx.y * 32;
    int tx = threadIdx.x, ty = threadIdx.y;   // 32 x 8
    for (int i = 0; i < 32; i += 8)
        tile[ty + i][tx] = in[(size_t)(by + ty + i) * cols + (bx + tx)];
    __syncthreads();
    for (int i = 0; i < 32; i += 8)
        out[(size_t)(bx + ty + i) * rows + (by + tx)] = __float2half(tile[tx][ty + i]);
}

// in: rows x cols f16  ->  out: cols x rows f32
__global__ void transpose_f16_f32_kernel(const __half* __restrict__ in, float* __restrict__ out,
                                         int rows, int cols) {
    __shared__ float tile[32][33];
    int bx = blockIdx.x * 32, by = blockIdx.y * 32;
    int tx = threadIdx.x, ty = threadIdx.y;
    for (int i = 0; i < 32; i += 8)
        tile[ty + i][tx] = __half2float(in[(size_t)(by + ty + i) * cols + (bx + tx)]);
    __syncthreads();
    for (int i = 0; i < 32; i += 8)
        out[(size_t)(bx + ty + i) * rows + (by + tx)] = tile[tx][ty + i];
}

// ---------- fused spmm + LSTM gates, one block per output column ----------
// 256 threads = 512 batch lanes as half2. All KMAX entry loads are
// block-uniform scalar loads issued up-front; all KMAX h-row gathers issue
// unconditionally (pad slots read hot row 0 with val=0) -> 16 loads in
// flight per thread instead of a serialized 8-deep dependent chain.
template <bool FIRST, bool LAST>
__global__ __launch_bounds__(256) void lstm_iter_kernel(
        const __half2* __restrict__ hin,     // (N, B/2)
        __half2*       __restrict__ hout,    // (N, B/2)
        float2*        __restrict__ c,       // (N, B/2) fp32 pairs
        const int*     __restrict__ counts,  // N (column degrees)
        const unsigned int* __restrict__ ell,// N*KMAX packed entries
        const uint2*   __restrict__ ovf,     // overflow list
        const int*     __restrict__ ovf_cnt,
        const float4*  __restrict__ b4) {
    int col = blockIdx.x;
    int t = threadIdx.x;
    int cnt = counts[col];
    int m = (cnt < KMAX) ? cnt : KMAX;

    // phase 1: all entry words (scalar, independent; unwritten slots -> 0)
    unsigned int en[KMAX];
    #pragma unroll
    for (int j = 0; j < KMAX; ++j) {
        unsigned int p = ell[col * KMAX + j];   // always in-bounds
        en[j] = (j < m) ? p : 0u;               // row 0, val 0 for pads
    }
    // phase 2: all gathers issued back-to-back (independent)
    __half2 hv[KMAX];
    #pragma unroll
    for (int j = 0; j < KMAX; ++j)
        hv[j] = hin[(size_t)(en[j] & 0xFFFFu) * (B / 2) + t];
    // phase 3: accumulate
    float zx = 0.f, zy = 0.f;
    #pragma unroll
    for (int j = 0; j < KMAX; ++j) {
        float v = __half2float(__ushort_as_half((unsigned short)(en[j] >> 16)));
        float2 hf = __half22float2(hv[j]);
        zx = fmaf(v, hf.x, zx);
        zy = fmaf(v, hf.y, zy);
    }
    // rare overflow (deg > KMAX, ~0.3% of columns): scan the tiny spill list
    if (cnt > KMAX) {
        int novf = *ovf_cnt;
        for (int k = 0; k < novf; ++k) {
            uint2 o = ovf[k];
            if (o.x == (unsigned int)col) {
                unsigned int p = o.y;
                float v = __half2float(__ushort_as_half((unsigned short)(p >> 16)));
                float2 hf = __half22float2(hin[(size_t)(p & 0xFFFFu) * (B / 2) + t]);
                zx = fmaf(v, hf.x, zx);
                zy = fmaf(v, hf.y, zy);
            }
        }
    }

    float4 bb = b4[col];
    size_t idx = (size_t)col * (B / 2) + t;
    float2 cv = FIRST ? make_float2(0.f, 0.f) : c[idx];

    float i0 = sigmoid_(zx + bb.x), f0 = sigmoid_(zx + bb.y);
    float o0 = sigmoid_(zx + bb.z), g0 = tanh_(zx + bb.w);
    float cx = f0 * cv.x + i0 * g0;
    float hx = o0 * tanh_(cx);

    float i1 = sigmoid_(zy + bb.x), f1 = sigmoid_(zy + bb.y);
    float o1 = sigmoid_(zy + bb.z), g1 = tanh_(zy + bb.w);
    float cy = f1 * cv.y + i1 * g1;
    float hy = o1 * tanh_(cy);

    if (!LAST) c[idx] = make_float2(cx, cy);
    hout[idx] = __halves2half2(__float2half_rn(hx), __float2half_rn(hy));
}

extern "C" void kernel_launch(void* const* d_in, const int* in_sizes, int n_in,
                              void* d_out, int out_size, void* d_ws, size_t ws_size,
                              hipStream_t stream) {
    const float* x    = (const float*)d_in[0];
    const float* kern = (const float*)d_in[1];
    const float* b_i  = (const float*)d_in[2];
    const float* b_f  = (const float*)d_in[3];
    const float* b_o  = (const float*)d_in[4];
    const float* b_g  = (const float*)d_in[5];
    const int*   idxw = (const int*)d_in[6];

    char* ws = (char*)d_ws;
    __half2*      hA      = (__half2*)     (ws + 0);          // 16777216 B
    __half2*      hB      = (__half2*)     (ws + 16777216);   // 16777216 B
    float2*       c       = (float2*)      (ws + 33554432);   // 33554432 B
    unsigned int* ell     = (unsigned int*)(ws + 67108864);   // N*KMAX*4 = 1048576 B
    float4*       b4      = (float4*)      (ws + 68157440);   // 262144 B
    int*          counts  = (int*)         (ws + 68419584);   // 65536 B
    int*          ovf_cnt = (int*)         (ws + 68485120);   // 4 B (memset with counts)
    uint2*        ovf     = (uint2*)       (ws + 68485128);   // 32768 B

    // zero counts + ovf_cnt in one memset (adjacent)
    hipMemsetAsync(counts, 0, 65540, stream);

    fill_ell_kernel<<<NNZ / 256, 256, 0, stream>>>(idxw, kern, counts, ell, ovf, ovf_cnt);
    pack_bias_kernel<<<N / 256, 256, 0, stream>>>(b_i, b_f, b_o, b_g, b4);

    // xT : (B,N) f32 -> (N,B) f16 into hA
    transpose_f32_f16_kernel<<<dim3(N / 32, B / 32), dim3(32, 8), 0, stream>>>(
        x, (__half*)hA, B, N);

    // 4 iterations, ping-pong hA <-> hB; c in fp32 ws (no read on first,
    // no write on last).
    lstm_iter_kernel<true,  false><<<N, 256, 0, stream>>>(hA, hB, c, counts, ell, ovf, ovf_cnt, b4);
    lstm_iter_kernel<false, false><<<N, 256, 0, stream>>>(hB, hA, c, counts, ell, ovf, ovf_cnt, b4);
    lstm_iter_kernel<false, false><<<N, 256, 0, stream>>>(hA, hB, c, counts, ell, ovf, ovf_cnt, b4);
    lstm_iter_kernel<false, true ><<<N, 256, 0, stream>>>(hB, hA, c, counts, ell, ovf, ovf_cnt, b4);

    // final h in hA: (N,B) f16 -> (B,N) f32 into d_out
    transpose_f16_f32_kernel<<<dim3(B / 32, N / 32), dim3(32, 8), 0, stream>>>(
        (const __half*)hA, (float*)d_out, N, B);
}

// Round 6
// 239.915 us; speedup vs baseline: 4.2923x; 1.0700x over previous
//
#include <hip/hip_runtime.h>
#include <hip/hip_fp16.h>

#define N 16384
#define B 512
#define NNZ 131072
#define KMAX 16          // ELL width; Poisson(8) tail spills to overflow list

// ---------- math helpers ----------
__device__ __forceinline__ float rcp_(float x) {
    return __builtin_amdgcn_rcpf(x);    // raw v_rcp_f32, ~1 ulp
}
__device__ __forceinline__ float tanh_(float x) {
    // overflow-safe: exp(2x)->inf gives 1, exp(2x)->0 gives -1
    return 1.f - 2.f * rcp_(__expf(2.f * x) + 1.f);
}

// ---------- inline index dtype detection ----------
// int64 little-endian with values < 16384 => every odd 32-bit word is zero.
__device__ __forceinline__ int is64_(const int* __restrict__ w) {
    int a = 1;
    #pragma unroll
    for (int i = 1; i < 16; i += 2) a &= (w[i] == 0);
    return a;
}

// ---------- one-shot ELL build ----------
// ell[col*KMAX + slot] = (u16 row) | (f16 val << 16); overflow -> (col, packed) list.
__global__ void fill_ell_kernel(const int* __restrict__ w, const float* __restrict__ kern,
                                int* __restrict__ counts, unsigned int* __restrict__ ell,
                                uint2* __restrict__ ovf, int* __restrict__ ovf_cnt) {
    int k = blockIdx.x * 256 + threadIdx.x;
    int is64 = is64_(w);
    int row = is64 ? w[4 * k]     : w[2 * k];
    int col = is64 ? w[4 * k + 2] : w[2 * k + 1];
    unsigned int packed = (unsigned int)(unsigned short)row |
                          ((unsigned int)__half_as_ushort(__float2half_rn(kern[k])) << 16);
    int slot = atomicAdd(&counts[col], 1);
    if (slot < KMAX) {
        ell[col * KMAX + slot] = packed;
    } else {
        int pos = atomicAdd(ovf_cnt, 1);
        ovf[pos] = make_uint2((unsigned int)col, packed);
    }
}

// precompute gate constants: (e^-bi, e^-bf, e^-bo, e^-2bg)
// sigmoid(z+b) = 1/(1 + e^-b * e^-z);  tanh(z+bg) = (1 - Dg*E)/(1 + Dg*E), E = e^-2z
__global__ void pack_bias_kernel(const float* __restrict__ bi, const float* __restrict__ bf,
                                 const float* __restrict__ bo, const float* __restrict__ bg,
                                 float4* __restrict__ b4) {
    int i = blockIdx.x * 256 + threadIdx.x;
    b4[i] = make_float4(__expf(-bi[i]), __expf(-bf[i]), __expf(-bo[i]),
                        __expf(-2.f * bg[i]));
}

// ---------- transposes with dtype conversion ----------
// in: rows x cols f32  ->  out: cols x rows f16
__global__ void transpose_f32_f16_kernel(const float* __restrict__ in, __half* __restrict__ out,
                                         int rows, int cols) {
    __shared__ float tile[32][33];
    int bx = blockIdx.x * 32, by = blockIdx.y * 32;
    int tx = threadIdx.x, ty = threadIdx.y;   // 32 x 8
    for (int i = 0; i < 32; i += 8)
        tile[ty + i][tx] = in[(size_t)(by + ty + i) * cols + (bx + tx)];
    __syncthreads();
    for (int i = 0; i < 32; i += 8)
        out[(size_t)(bx + ty + i) * rows + (by + tx)] = __float2half(tile[tx][ty + i]);
}

// in: rows x cols f16  ->  out: cols x rows f32
__global__ void transpose_f16_f32_kernel(const __half* __restrict__ in, float* __restrict__ out,
                                         int rows, int cols) {
    __shared__ float tile[32][33];
    int bx = blockIdx.x * 32, by = blockIdx.y * 32;
    int tx = threadIdx.x, ty = threadIdx.y;
    for (int i = 0; i < 32; i += 8)
        tile[ty + i][tx] = __half2float(in[(size_t)(by + ty + i) * cols + (bx + tx)]);
    __syncthreads();
    for (int i = 0; i < 32; i += 8)
        out[(size_t)(bx + ty + i) * rows + (by + tx)] = tile[tx][ty + i];
}

// ---------- fused spmm + LSTM gates, XCD-locality batch split ----------
// Grid 16384 blocks x 256 threads. Block (colg, q): 8 cols x 64 batch.
//   q = blockIdx & 7  -> batch eighth; with round-robin dispatch, all blocks of
//   a given q land on one XCD, so each XCD's L2 only caches its 2 MB h-slice
//   (plus the slice it wrote last iteration -> cross-dispatch L2 reuse).
// Each 32-lane group owns one column; gather rows are 128 B contiguous.
template <bool FIRST, bool LAST>
__global__ __launch_bounds__(256) void lstm_iter_kernel(
        const __half2* __restrict__ hin,     // (N, B/2)
        __half2*       __restrict__ hout,    // (N, B/2)
        __half2*       __restrict__ c,       // (N, B/2) fp16 pairs
        const int*     __restrict__ counts,  // N (column degrees)
        const uint4*   __restrict__ ell4,    // N*KMAX packed entries as uint4
        const uint2*   __restrict__ ovf,     // overflow list
        const int*     __restrict__ ovf_cnt,
        const float4*  __restrict__ b4) {
    const int t    = threadIdx.x;
    const int lane = t & 31;                 // half2 batch pos within eighth
    const int sub  = t >> 5;                 // which of the block's 8 cols
    const int q    = blockIdx.x & 7;         // batch eighth (~XCD id)
    const int col  = (blockIdx.x >> 3) * 8 + sub;
    const int boff = q * 32 + lane;          // half2 index within a row

    int cnt = counts[col];
    int m = (cnt < KMAX) ? cnt : KMAX;

    // phase 1: entry words (4 x 16B loads, uniform per 32-lane group)
    uint4 e0 = ell4[col * 4 + 0];
    uint4 e1 = ell4[col * 4 + 1];
    uint4 e2 = ell4[col * 4 + 2];
    uint4 e3 = ell4[col * 4 + 3];
    unsigned int en[KMAX] = { e0.x, e0.y, e0.z, e0.w, e1.x, e1.y, e1.z, e1.w,
                              e2.x, e2.y, e2.z, e2.w, e3.x, e3.y, e3.z, e3.w };
    #pragma unroll
    for (int j = 0; j < KMAX; ++j)
        if (j >= m) en[j] = 0u;              // pads: row 0, val 0

    // phase 2: all gathers issued back-to-back (independent, 16 in flight)
    __half2 hv[KMAX];
    #pragma unroll
    for (int j = 0; j < KMAX; ++j)
        hv[j] = hin[(en[j] & 0xFFFFu) * (B / 2) + boff];

    // phase 3: accumulate
    float zx = 0.f, zy = 0.f;
    #pragma unroll
    for (int j = 0; j < KMAX; ++j) {
        float v = __half2float(__ushort_as_half((unsigned short)(en[j] >> 16)));
        float2 hf = __half22float2(hv[j]);
        zx = fmaf(v, hf.x, zx);
        zy = fmaf(v, hf.y, zy);
    }
    // rare overflow (deg > KMAX, ~0.3% of columns)
    if (cnt > KMAX) {
        int novf = *ovf_cnt;
        for (int k = 0; k < novf; ++k) {
            uint2 o = ovf[k];
            if (o.x == (unsigned int)col) {
                unsigned int p = o.y;
                float v = __half2float(__ushort_as_half((unsigned short)(p >> 16)));
                float2 hf = __half22float2(hin[(p & 0xFFFFu) * (B / 2) + boff]);
                zx = fmaf(v, hf.x, zx);
                zy = fmaf(v, hf.y, zy);
            }
        }
    }

    float4 bb = b4[col];                     // (e^-bi, e^-bf, e^-bo, e^-2bg)
    unsigned int idx = (unsigned int)col * (B / 2) + boff;
    float2 cv = FIRST ? make_float2(0.f, 0.f) : __half22float2(c[idx]);

    // element x
    float ezx = __expf(-zx);
    float i0 = rcp_(fmaf(bb.x, ezx, 1.f));
    float f0 = rcp_(fmaf(bb.y, ezx, 1.f));
    float o0 = rcp_(fmaf(bb.z, ezx, 1.f));
    float dEx = bb.w * ezx * ezx;
    float g0 = (1.f - dEx) * rcp_(1.f + dEx);
    float cx = f0 * cv.x + i0 * g0;
    float hx = o0 * tanh_(cx);

    // element y
    float ezy = __expf(-zy);
    float i1 = rcp_(fmaf(bb.x, ezy, 1.f));
    float f1 = rcp_(fmaf(bb.y, ezy, 1.f));
    float o1 = rcp_(fmaf(bb.z, ezy, 1.f));
    float dEy = bb.w * ezy * ezy;
    float g1 = (1.f - dEy) * rcp_(1.f + dEy);
    float cy = f1 * cv.y + i1 * g1;
    float hy = o1 * tanh_(cy);

    if (!LAST) c[idx] = __halves2half2(__float2half_rn(cx), __float2half_rn(cy));
    hout[idx] = __halves2half2(__float2half_rn(hx), __float2half_rn(hy));
}

extern "C" void kernel_launch(void* const* d_in, const int* in_sizes, int n_in,
                              void* d_out, int out_size, void* d_ws, size_t ws_size,
                              hipStream_t stream) {
    const float* x    = (const float*)d_in[0];
    const float* kern = (const float*)d_in[1];
    const float* b_i  = (const float*)d_in[2];
    const float* b_f  = (const float*)d_in[3];
    const float* b_o  = (const float*)d_in[4];
    const float* b_g  = (const float*)d_in[5];
    const int*   idxw = (const int*)d_in[6];

    char* ws = (char*)d_ws;
    __half2*      hA      = (__half2*)     (ws + 0);          // 16777216 B
    __half2*      hB      = (__half2*)     (ws + 16777216);   // 16777216 B
    __half2*      c       = (__half2*)     (ws + 33554432);   // 16777216 B
    unsigned int* ell     = (unsigned int*)(ws + 50331648);   // 1048576 B
    float4*       b4      = (float4*)      (ws + 51380224);   // 262144 B
    int*          counts  = (int*)         (ws + 51642368);   // 65536 B
    int*          ovf_cnt = (int*)         (ws + 51707904);   // 4 B
    uint2*        ovf     = (uint2*)       (ws + 51707912);   // 32768 B

    // zero counts + ovf_cnt in one memset (adjacent)
    hipMemsetAsync(counts, 0, 65540, stream);

    fill_ell_kernel<<<NNZ / 256, 256, 0, stream>>>(idxw, kern, counts, ell, ovf, ovf_cnt);
    pack_bias_kernel<<<N / 256, 256, 0, stream>>>(b_i, b_f, b_o, b_g, b4);

    // xT : (B,N) f32 -> (N,B) f16 into hA
    transpose_f32_f16_kernel<<<dim3(N / 32, B / 32), dim3(32, 8), 0, stream>>>(
        x, (__half*)hA, B, N);

    // 4 iterations, ping-pong hA <-> hB; c in fp16 ws (no read first, no write last)
    const uint4* ell4 = (const uint4*)ell;
    lstm_iter_kernel<true,  false><<<N, 256, 0, stream>>>(hA, hB, c, counts, ell4, ovf, ovf_cnt, b4);
    lstm_iter_kernel<false, false><<<N, 256, 0, stream>>>(hB, hA, c, counts, ell4, ovf, ovf_cnt, b4);
    lstm_iter_kernel<false, false><<<N, 256, 0, stream>>>(hA, hB, c, counts, ell4, ovf, ovf_cnt, b4);
    lstm_iter_kernel<false, true ><<<N, 256, 0, stream>>>(hB, hA, c, counts, ell4, ovf, ovf_cnt, b4);

    // final h in hA: (N,B) f16 -> (B,N) f32 into d_out
    transpose_f16_f32_kernel<<<dim3(B / 32, N / 32), dim3(32, 8), 0, stream>>>(
        (const __half*)hA, (float*)d_out, N, B);
}

// Round 7
// 226.764 us; speedup vs baseline: 4.5412x; 1.0580x over previous
//
#include <hip/hip_runtime.h>
#include <hip/hip_fp16.h>

#define N 16384
#define B 512
#define NNZ 131072
#define KMAX 16          // ELL width; Poisson(8) tail spills to overflow list

// ---------- math helpers ----------
__device__ __forceinline__ float rcp_(float x) {
    return __builtin_amdgcn_rcpf(x);    // raw v_rcp_f32, ~1 ulp
}
__device__ __forceinline__ float tanh_(float x) {
    // overflow-safe: exp(2x)->inf gives 1, exp(2x)->0 gives -1
    return 1.f - 2.f * rcp_(__expf(2.f * x) + 1.f);
}
__device__ __forceinline__ __half2 as_h2(unsigned int u) {
    __half2 h;
    __builtin_memcpy(&h, &u, 4);
    return h;
}
__device__ __forceinline__ unsigned int pack_h2(float a, float b) {
    __half2 h = __halves2half2(__float2half_rn(a), __float2half_rn(b));
    unsigned int u;
    __builtin_memcpy(&u, &h, 4);
    return u;
}

// ---------- inline index dtype detection ----------
// int64 little-endian with values < 16384 => every odd 32-bit word is zero.
__device__ __forceinline__ int is64_(const int* __restrict__ w) {
    int a = 1;
    #pragma unroll
    for (int i = 1; i < 16; i += 2) a &= (w[i] == 0);
    return a;
}

// ---------- one-shot ELL build (ell pre-zeroed by memset) ----------
// ell[col*KMAX + slot] = (u16 row) | (f16 val << 16); overflow -> (col, packed).
__global__ void fill_ell_kernel(const int* __restrict__ w, const float* __restrict__ kern,
                                int* __restrict__ counts, unsigned int* __restrict__ ell,
                                uint2* __restrict__ ovf, int* __restrict__ ovf_cnt) {
    int k = blockIdx.x * 256 + threadIdx.x;
    int is64 = is64_(w);
    int row = is64 ? w[4 * k]     : w[2 * k];
    int col = is64 ? w[4 * k + 2] : w[2 * k + 1];
    unsigned int packed = (unsigned int)(unsigned short)row |
                          ((unsigned int)__half_as_ushort(__float2half_rn(kern[k])) << 16);
    int slot = atomicAdd(&counts[col], 1);
    if (slot < KMAX) {
        ell[col * KMAX + slot] = packed;
    } else {
        int pos = atomicAdd(ovf_cnt, 1);
        ovf[pos] = make_uint2((unsigned int)col, packed);
    }
}

// precompute gate constants: (e^-bi, e^-bf, e^-bo, e^-2bg)
// sigmoid(z+b) = 1/(1 + e^-b e^-z);  tanh(z+bg) = 2/(1 + e^-2bg e^-2z) - 1
__global__ void pack_bias_kernel(const float* __restrict__ bi, const float* __restrict__ bf,
                                 const float* __restrict__ bo, const float* __restrict__ bg,
                                 float4* __restrict__ b4) {
    int i = blockIdx.x * 256 + threadIdx.x;
    b4[i] = make_float4(__expf(-bi[i]), __expf(-bf[i]), __expf(-bo[i]),
                        __expf(-2.f * bg[i]));
}

// ---------- input transpose: (B,N) f32 -> (N,B) f16 ----------
__global__ void transpose_f32_f16_kernel(const float* __restrict__ in, __half* __restrict__ out,
                                         int rows, int cols) {
    __shared__ float tile[32][33];
    int bx = blockIdx.x * 32, by = blockIdx.y * 32;
    int tx = threadIdx.x, ty = threadIdx.y;   // 32 x 8
    for (int i = 0; i < 32; i += 8)
        tile[ty + i][tx] = in[(size_t)(by + ty + i) * cols + (bx + tx)];
    __syncthreads();
    for (int i = 0; i < 32; i += 8)
        out[(size_t)(bx + ty + i) * rows + (by + tx)] = __float2half(tile[tx][ty + i]);
}

// ---------- fused spmm + LSTM gates ----------
// Grid 8192 = (N/16) x 8. Block: 16 cols x 64 batch (one eighth).
//   q = blockIdx & 7 -> batch eighth (XCD-locality: round-robin dispatch keeps
//   each q's 2 MB h-slice inside one XCD's L2 across dispatches).
// Thread: 1 col x 4 batch elems (uint2 = 4 f16). 16-lane col group gathers a
// contiguous 128 B row segment per entry; all 16 gathers independent.
// ELL pads are zero (row 0, val 0) -> no select, fma adds 0.
// LAST: writes transposed f32 directly to out via an LDS tile (no epilogue
// transpose kernel); otherwise writes f16 h for the next iteration.
template <bool FIRST, bool LAST>
__global__ __launch_bounds__(256) void lstm_iter_kernel(
        const uint2*  __restrict__ hin,     // (N, B/4) packed 4xf16
        uint2*        __restrict__ hout,    // (N, B/4)
        uint2*        __restrict__ c,       // (N, B/4) packed 4xf16
        float*        __restrict__ out,     // (B, N) f32 (LAST only)
        const int*    __restrict__ counts,  // N column degrees (overflow check)
        const uint4*  __restrict__ ell4,    // N*KMAX entries as uint4
        const uint2*  __restrict__ ovf,
        const int*    __restrict__ ovf_cnt,
        const float4* __restrict__ b4) {
    const int t      = threadIdx.x;
    const int lane16 = t & 15;
    const int sub    = t >> 4;               // col within block's 16
    const int q      = blockIdx.x & 7;       // batch eighth
    const int col    = (blockIdx.x >> 3) * 16 + sub;
    const int boff   = q * 16 + lane16;      // uint2 index within a row (B/4 = 128)

    // phase 1: entry words (4 x 16B, uniform per 16-lane group)
    uint4 e0 = ell4[col * 4 + 0];
    uint4 e1 = ell4[col * 4 + 1];
    uint4 e2 = ell4[col * 4 + 2];
    uint4 e3 = ell4[col * 4 + 3];
    unsigned int en[KMAX] = { e0.x, e0.y, e0.z, e0.w, e1.x, e1.y, e1.z, e1.w,
                              e2.x, e2.y, e2.z, e2.w, e3.x, e3.y, e3.z, e3.w };

    // phase 2: 16 independent 8 B gathers
    uint2 hv[KMAX];
    #pragma unroll
    for (int j = 0; j < KMAX; ++j)
        hv[j] = hin[(en[j] & 0xFFFFu) * (B / 4) + boff];

    // phase 3: accumulate 4 batch elems (f32 accum; fma_mix-friendly)
    float z[4] = {0.f, 0.f, 0.f, 0.f};
    #pragma unroll
    for (int j = 0; j < KMAX; ++j) {
        float v = __half2float(__ushort_as_half((unsigned short)(en[j] >> 16)));
        float2 fa = __half22float2(as_h2(hv[j].x));
        float2 fb = __half22float2(as_h2(hv[j].y));
        z[0] = fmaf(v, fa.x, z[0]);
        z[1] = fmaf(v, fa.y, z[1]);
        z[2] = fmaf(v, fb.x, z[2]);
        z[3] = fmaf(v, fb.y, z[3]);
    }
    // rare overflow (deg > KMAX, ~0.3% of columns)
    int cnt = counts[col];
    if (cnt > KMAX) {
        int novf = *ovf_cnt;
        for (int k = 0; k < novf; ++k) {
            uint2 o = ovf[k];
            if (o.x == (unsigned int)col) {
                unsigned int p = o.y;
                float v = __half2float(__ushort_as_half((unsigned short)(p >> 16)));
                uint2 hx = hin[(p & 0xFFFFu) * (B / 4) + boff];
                float2 fa = __half22float2(as_h2(hx.x));
                float2 fb = __half22float2(as_h2(hx.y));
                z[0] = fmaf(v, fa.x, z[0]);
                z[1] = fmaf(v, fa.y, z[1]);
                z[2] = fmaf(v, fb.x, z[2]);
                z[3] = fmaf(v, fb.y, z[3]);
            }
        }
    }

    const float4 bb = b4[col];               // (e^-bi, e^-bf, e^-bo, e^-2bg)
    const unsigned int idx = (unsigned int)col * (B / 4) + boff;

    float cv[4] = {0.f, 0.f, 0.f, 0.f};
    if (!FIRST) {
        uint2 cr = c[idx];
        float2 ca = __half22float2(as_h2(cr.x));
        float2 cb = __half22float2(as_h2(cr.y));
        cv[0] = ca.x; cv[1] = ca.y; cv[2] = cb.x; cv[3] = cb.y;
    }

    float hh[4], ch[4];
    #pragma unroll
    for (int e = 0; e < 4; ++e) {
        float ez = __expf(-z[e]);
        float ig = rcp_(fmaf(bb.x, ez, 1.f));
        float fg = rcp_(fmaf(bb.y, ez, 1.f));
        float og = rcp_(fmaf(bb.z, ez, 1.f));
        float dE = bb.w * ez * ez;
        float gg = fmaf(2.f, rcp_(1.f + dE), -1.f);   // tanh(z+bg)
        float cn = fg * cv[e] + ig * gg;
        ch[e] = cn;
        hh[e] = og * tanh_(cn);
    }

    if (!LAST) {
        c[idx]    = make_uint2(pack_h2(ch[0], ch[1]), pack_h2(ch[2], ch[3]));
        hout[idx] = make_uint2(pack_h2(hh[0], hh[1]), pack_h2(hh[2], hh[3]));
    } else {
        // transposed f32 write: block tile = 64 batch rows x 16 cols
        __shared__ float tile[64 * 17];
        #pragma unroll
        for (int e = 0; e < 4; ++e)
            tile[(lane16 * 4 + e) * 17 + sub] = hh[e];
        __syncthreads();
        const int col0 = (blockIdx.x >> 3) * 16;
        #pragma unroll
        for (int k = 0; k < 4; ++k) {
            int i = k * 256 + t;
            int r = i >> 4;        // batch row 0..63
            int cc = i & 15;       // col 0..15
            out[(size_t)(q * 64 + r) * N + col0 + cc] = tile[r * 17 + cc];
        }
    }
}

extern "C" void kernel_launch(void* const* d_in, const int* in_sizes, int n_in,
                              void* d_out, int out_size, void* d_ws, size_t ws_size,
                              hipStream_t stream) {
    const float* x    = (const float*)d_in[0];
    const float* kern = (const float*)d_in[1];
    const float* b_i  = (const float*)d_in[2];
    const float* b_f  = (const float*)d_in[3];
    const float* b_o  = (const float*)d_in[4];
    const float* b_g  = (const float*)d_in[5];
    const int*   idxw = (const int*)d_in[6];

    char* ws = (char*)d_ws;
    uint2*        hA      = (uint2*)       (ws + 0);          // 16777216 B
    uint2*        hB      = (uint2*)       (ws + 16777216);   // 16777216 B
    uint2*        c       = (uint2*)       (ws + 33554432);   // 16777216 B
    unsigned int* ell     = (unsigned int*)(ws + 50331648);   // 1048576 B (zeroed)
    int*          counts  = (int*)         (ws + 51380224);   // 65536 B   (zeroed)
    int*          ovf_cnt = (int*)         (ws + 51445760);   // 4 B       (zeroed)
    uint2*        ovf     = (uint2*)       (ws + 51445768);   // 32768 B
    float4*       b4      = (float4*)      (ws + 51478536 + 120);  // 16B-aligned @51478656

    // one memset zeroes ell + counts + ovf_cnt (contiguous)
    hipMemsetAsync(ell, 0, 1048576 + 65536 + 4, stream);

    fill_ell_kernel<<<NNZ / 256, 256, 0, stream>>>(idxw, kern, counts, ell, ovf, ovf_cnt);
    pack_bias_kernel<<<N / 256, 256, 0, stream>>>(b_i, b_f, b_o, b_g, b4);

    // xT : (B,N) f32 -> (N,B) f16 into hA
    transpose_f32_f16_kernel<<<dim3(N / 32, B / 32), dim3(32, 8), 0, stream>>>(
        x, (__half*)hA, B, N);

    const uint4* ell4 = (const uint4*)ell;
    float* out = (float*)d_out;
    const int GRID = (N / 16) * 8;   // 8192

    lstm_iter_kernel<true,  false><<<GRID, 256, 0, stream>>>(hA, hB, c, out, counts, ell4, ovf, ovf_cnt, b4);
    lstm_iter_kernel<false, false><<<GRID, 256, 0, stream>>>(hB, hA, c, out, counts, ell4, ovf, ovf_cnt, b4);
    lstm_iter_kernel<false, false><<<GRID, 256, 0, stream>>>(hA, hB, c, out, counts, ell4, ovf, ovf_cnt, b4);
    // LAST: writes transposed f32 directly into d_out (hout unused)
    lstm_iter_kernel<false, true ><<<GRID, 256, 0, stream>>>(hB, hA, c, out, counts, ell4, ovf, ovf_cnt, b4);
}

// Round 8
// 208.800 us; speedup vs baseline: 4.9319x; 1.0860x over previous
//
#include <hip/hip_runtime.h>
#include <hip/hip_fp16.h>

#define N 16384
#define B 512
#define NNZ 131072
#define KMAX 16          // ELL width; Poisson(8) tail spills to overflow list

// ---------- math helpers ----------
__device__ __forceinline__ float rcp_(float x) {
    return __builtin_amdgcn_rcpf(x);    // raw v_rcp_f32, ~1 ulp
}
__device__ __forceinline__ float tanh_(float x) {
    // overflow-safe: exp(2x)->inf gives 1, exp(2x)->0 gives -1
    return 1.f - 2.f * rcp_(__expf(2.f * x) + 1.f);
}
__device__ __forceinline__ __half2 as_h2(unsigned int u) {
    __half2 h;
    __builtin_memcpy(&h, &u, 4);
    return h;
}
__device__ __forceinline__ unsigned int pack_h2(float a, float b) {
    __half2 h = __halves2half2(__float2half_rn(a), __float2half_rn(b));
    unsigned int u;
    __builtin_memcpy(&u, &h, 4);
    return u;
}

// ---------- inline index dtype detection ----------
// int64 little-endian with values < 16384 => every odd 32-bit word is zero.
__device__ __forceinline__ int is64_(const int* __restrict__ w) {
    int a = 1;
    #pragma unroll
    for (int i = 1; i < 16; i += 2) a &= (w[i] == 0);
    return a;
}

// ---------- fused prep: transpose + ELL build + bias pack in ONE dispatch ----------
// blocks [0, 8192)        : xT transpose (B,N) f32 -> (N,B) f16
// blocks [8192, 8704)     : fill_ell (ell pre-zeroed by memset)
// blocks [8704, 8768)     : pack gate constants
__global__ __launch_bounds__(256) void prep_kernel(
        const float* __restrict__ x, __half* __restrict__ xT,
        const int* __restrict__ w, const float* __restrict__ kern,
        int* __restrict__ counts, unsigned int* __restrict__ ell,
        uint2* __restrict__ ovf, int* __restrict__ ovf_cnt,
        const float* __restrict__ bi, const float* __restrict__ bf,
        const float* __restrict__ bo, const float* __restrict__ bg,
        float4* __restrict__ b4) {
    const int bid = blockIdx.x;
    const int t = threadIdx.x;
    if (bid < 8192) {
        // 32x32 transpose tile; threads as 32x8
        __shared__ float tile[32][33];
        int bx = (bid & 511) * 32;   // N offset
        int by = (bid >> 9) * 32;    // B offset
        int tx = t & 31, ty = t >> 5;
        #pragma unroll
        for (int i = 0; i < 32; i += 8)
            tile[ty + i][tx] = x[(size_t)(by + ty + i) * N + bx + tx];
        __syncthreads();
        #pragma unroll
        for (int i = 0; i < 32; i += 8)
            xT[(size_t)(bx + ty + i) * B + by + tx] = __float2half(tile[tx][ty + i]);
    } else if (bid < 8704) {
        int k = (bid - 8192) * 256 + t;
        int is64 = is64_(w);
        int row = is64 ? w[4 * k]     : w[2 * k];
        int col = is64 ? w[4 * k + 2] : w[2 * k + 1];
        unsigned int packed = (unsigned int)(unsigned short)row |
                              ((unsigned int)__half_as_ushort(__float2half_rn(kern[k])) << 16);
        int slot = atomicAdd(&counts[col], 1);
        if (slot < KMAX) {
            ell[col * KMAX + slot] = packed;
        } else {
            int pos = atomicAdd(ovf_cnt, 1);
            ovf[pos] = make_uint2((unsigned int)col, packed);
        }
    } else {
        // gate constants: (e^-bi, e^-bf, e^-bo, e^-2bg)
        // sigmoid(z+b) = 1/(1 + e^-b e^-z); tanh(z+bg) = 2/(1 + e^-2bg e^-2z) - 1
        int i = (bid - 8704) * 256 + t;
        b4[i] = make_float4(__expf(-bi[i]), __expf(-bf[i]), __expf(-bo[i]),
                            __expf(-2.f * bg[i]));
    }
}

// ---------- fused spmm + LSTM gates ----------
// Grid 4096 = (N/16) x 4. Block: 16 cols x 128 batch (one quarter).
//   q = blockIdx & 3 -> batch quarter; round-robin dispatch pins each q to
//   2 XCDs whose L2 then only caches that quarter's 4 MB h-slice.
// Thread: 1 col x 8 batch elems (uint4 = 8 f16). 16-lane col group gathers a
// contiguous 256 B row segment per entry; gathers issued in two 8-deep rounds
// (ILP 8) to stay under the 128-VGPR / 4-waves-per-SIMD occupancy cap.
// ELL pads are zero (row 0, val 0) -> fma adds 0, no selects.
// LAST: writes transposed f32 directly to out via an LDS tile.
template <bool FIRST, bool LAST>
__global__ __launch_bounds__(256, 4) void lstm_iter_kernel(
        const uint4*  __restrict__ hin,     // (N, B/8) packed 8xf16
        uint4*        __restrict__ hout,    // (N, B/8)
        uint4*        __restrict__ c,       // (N, B/8) packed 8xf16
        float*        __restrict__ out,     // (B, N) f32 (LAST only)
        const int*    __restrict__ counts,  // N column degrees (overflow check)
        const uint4*  __restrict__ ell4,    // N*KMAX entries as uint4
        const uint2*  __restrict__ ovf,
        const int*    __restrict__ ovf_cnt,
        const float4* __restrict__ b4) {
    const int t      = threadIdx.x;
    const int lane16 = t & 15;
    const int sub    = t >> 4;               // col within block's 16
    const int q      = blockIdx.x & 3;       // batch quarter
    const int col    = (blockIdx.x >> 2) * 16 + sub;
    const int boff   = q * 16 + lane16;      // uint4 index within a row (B/8 = 64)

    // entry words (4 x 16B, uniform per 16-lane group)
    uint4 e0 = ell4[col * 4 + 0];
    uint4 e1 = ell4[col * 4 + 1];
    uint4 e2 = ell4[col * 4 + 2];
    uint4 e3 = ell4[col * 4 + 3];
    unsigned int en[KMAX] = { e0.x, e0.y, e0.z, e0.w, e1.x, e1.y, e1.z, e1.w,
                              e2.x, e2.y, e2.z, e2.w, e3.x, e3.y, e3.z, e3.w };

    float z[8] = {0.f, 0.f, 0.f, 0.f, 0.f, 0.f, 0.f, 0.f};
    #pragma unroll
    for (int half = 0; half < 2; ++half) {
        uint4 hv[8];
        #pragma unroll
        for (int j = 0; j < 8; ++j)
            hv[j] = hin[(en[half * 8 + j] & 0xFFFFu) * (B / 8) + boff];
        #pragma unroll
        for (int j = 0; j < 8; ++j) {
            float v = __half2float(__ushort_as_half((unsigned short)(en[half * 8 + j] >> 16)));
            float2 f0 = __half22float2(as_h2(hv[j].x));
            float2 f1 = __half22float2(as_h2(hv[j].y));
            float2 f2 = __half22float2(as_h2(hv[j].z));
            float2 f3 = __half22float2(as_h2(hv[j].w));
            z[0] = fmaf(v, f0.x, z[0]);  z[1] = fmaf(v, f0.y, z[1]);
            z[2] = fmaf(v, f1.x, z[2]);  z[3] = fmaf(v, f1.y, z[3]);
            z[4] = fmaf(v, f2.x, z[4]);  z[5] = fmaf(v, f2.y, z[5]);
            z[6] = fmaf(v, f3.x, z[6]);  z[7] = fmaf(v, f3.y, z[7]);
        }
    }
    // rare overflow (deg > KMAX, ~0.3% of columns)
    int cnt = counts[col];
    if (cnt > KMAX) {
        int novf = *ovf_cnt;
        for (int k = 0; k < novf; ++k) {
            uint2 o = ovf[k];
            if (o.x == (unsigned int)col) {
                unsigned int p = o.y;
                float v = __half2float(__ushort_as_half((unsigned short)(p >> 16)));
                uint4 hx = hin[(p & 0xFFFFu) * (B / 8) + boff];
                float2 f0 = __half22float2(as_h2(hx.x));
                float2 f1 = __half22float2(as_h2(hx.y));
                float2 f2 = __half22float2(as_h2(hx.z));
                float2 f3 = __half22float2(as_h2(hx.w));
                z[0] = fmaf(v, f0.x, z[0]);  z[1] = fmaf(v, f0.y, z[1]);
                z[2] = fmaf(v, f1.x, z[2]);  z[3] = fmaf(v, f1.y, z[3]);
                z[4] = fmaf(v, f2.x, z[4]);  z[5] = fmaf(v, f2.y, z[5]);
                z[6] = fmaf(v, f3.x, z[6]);  z[7] = fmaf(v, f3.y, z[7]);
            }
        }
    }

    const float4 bb = b4[col];               // (e^-bi, e^-bf, e^-bo, e^-2bg)
    const unsigned int idx = (unsigned int)col * (B / 8) + boff;

    float cv[8] = {0.f, 0.f, 0.f, 0.f, 0.f, 0.f, 0.f, 0.f};
    if (!FIRST) {
        uint4 cr = c[idx];
        float2 c0 = __half22float2(as_h2(cr.x));
        float2 c1 = __half22float2(as_h2(cr.y));
        float2 c2 = __half22float2(as_h2(cr.z));
        float2 c3 = __half22float2(as_h2(cr.w));
        cv[0] = c0.x; cv[1] = c0.y; cv[2] = c1.x; cv[3] = c1.y;
        cv[4] = c2.x; cv[5] = c2.y; cv[6] = c3.x; cv[7] = c3.y;
    }

    float hh[8], ch[8];
    #pragma unroll
    for (int e = 0; e < 8; ++e) {
        float ez = __expf(-z[e]);
        float ig = rcp_(fmaf(bb.x, ez, 1.f));
        float fg = rcp_(fmaf(bb.y, ez, 1.f));
        float og = rcp_(fmaf(bb.z, ez, 1.f));
        float dE = bb.w * ez * ez;
        float gg = fmaf(2.f, rcp_(1.f + dE), -1.f);   // tanh(z+bg)
        float cn = fg * cv[e] + ig * gg;
        ch[e] = cn;
        hh[e] = og * tanh_(cn);
    }

    if (!LAST) {
        c[idx]    = make_uint4(pack_h2(ch[0], ch[1]), pack_h2(ch[2], ch[3]),
                               pack_h2(ch[4], ch[5]), pack_h2(ch[6], ch[7]));
        hout[idx] = make_uint4(pack_h2(hh[0], hh[1]), pack_h2(hh[2], hh[3]),
                               pack_h2(hh[4], hh[5]), pack_h2(hh[6], hh[7]));
    } else {
        // transposed f32 write: block tile = 128 batch rows x 16 cols
        __shared__ float tile[128 * 17];
        #pragma unroll
        for (int e = 0; e < 8; ++e)
            tile[(lane16 * 8 + e) * 17 + sub] = hh[e];
        __syncthreads();
        const int col0 = (blockIdx.x >> 2) * 16;
        #pragma unroll
        for (int k = 0; k < 8; ++k) {
            int i = k * 256 + t;
            int r = i >> 4;        // batch row 0..127
            int cc = i & 15;       // col 0..15
            out[(size_t)(q * 128 + r) * N + col0 + cc] = tile[r * 17 + cc];
        }
    }
}

extern "C" void kernel_launch(void* const* d_in, const int* in_sizes, int n_in,
                              void* d_out, int out_size, void* d_ws, size_t ws_size,
                              hipStream_t stream) {
    const float* x    = (const float*)d_in[0];
    const float* kern = (const float*)d_in[1];
    const float* b_i  = (const float*)d_in[2];
    const float* b_f  = (const float*)d_in[3];
    const float* b_o  = (const float*)d_in[4];
    const float* b_g  = (const float*)d_in[5];
    const int*   idxw = (const int*)d_in[6];

    char* ws = (char*)d_ws;
    uint4*        hA      = (uint4*)       (ws + 0);          // 16777216 B
    uint4*        hB      = (uint4*)       (ws + 16777216);   // 16777216 B
    uint4*        c       = (uint4*)       (ws + 33554432);   // 16777216 B
    unsigned int* ell     = (unsigned int*)(ws + 50331648);   // 1048576 B (zeroed)
    int*          counts  = (int*)         (ws + 51380224);   // 65536 B   (zeroed)
    int*          ovf_cnt = (int*)         (ws + 51445760);   // 4 B       (zeroed)
    uint2*        ovf     = (uint2*)       (ws + 51445768);   // 32768 B
    float4*       b4      = (float4*)      (ws + 51478656);   // 262144 B (16B-aligned)

    // one memset zeroes ell + counts + ovf_cnt (contiguous)
    hipMemsetAsync(ell, 0, 1048576 + 65536 + 4, stream);

    // fused prep: transpose (8192) + fill_ell (512) + pack_bias (64)
    prep_kernel<<<8768, 256, 0, stream>>>(x, (__half*)hA, idxw, kern,
                                          counts, ell, ovf, ovf_cnt,
                                          b_i, b_f, b_o, b_g, b4);

    const uint4* ell4 = (const uint4*)ell;
    float* out = (float*)d_out;
    const int GRID = (N / 16) * 4;   // 4096

    lstm_iter_kernel<true,  false><<<GRID, 256, 0, stream>>>(hA, hB, c, out, counts, ell4, ovf, ovf_cnt, b4);
    lstm_iter_kernel<false, false><<<GRID, 256, 0, stream>>>(hB, hA, c, out, counts, ell4, ovf, ovf_cnt, b4);
    lstm_iter_kernel<false, false><<<GRID, 256, 0, stream>>>(hA, hB, c, out, counts, ell4, ovf, ovf_cnt, b4);
    // LAST: writes transposed f32 directly into d_out (hout unused)
    lstm_iter_kernel<false, true ><<<GRID, 256, 0, stream>>>(hB, hA, c, out, counts, ell4, ovf, ovf_cnt, b4);
}

// Round 9
// 194.924 us; speedup vs baseline: 5.2830x; 1.0712x over previous
//
#include <hip/hip_runtime.h>
#include <hip/hip_fp16.h>

#define N 16384
#define B 512
#define NNZ 131072
#define KMAX 16          // ELL width; Poisson(8) tail spills to overflow list

// ---------- math helpers ----------
__device__ __forceinline__ float rcp_(float x) {
    return __builtin_amdgcn_rcpf(x);    // raw v_rcp_f32, ~1 ulp
}
__device__ __forceinline__ float tanh_(float x) {
    // overflow-safe: exp(2x)->inf gives 1, exp(2x)->0 gives -1
    return 1.f - 2.f * rcp_(__expf(2.f * x) + 1.f);
}
__device__ __forceinline__ __half2 as_h2(unsigned int u) {
    __half2 h;
    __builtin_memcpy(&h, &u, 4);
    return h;
}
__device__ __forceinline__ unsigned int pack_h2(float a, float b) {
    __half2 h = __halves2half2(__float2half_rn(a), __float2half_rn(b));
    unsigned int u;
    __builtin_memcpy(&u, &h, 4);
    return u;
}

// ---------- inline index dtype detection ----------
// int64 little-endian with values < 16384 => every odd 32-bit word is zero.
__device__ __forceinline__ int is64_(const int* __restrict__ w) {
    int a = 1;
    #pragma unroll
    for (int i = 1; i < 16; i += 2) a &= (w[i] == 0);
    return a;
}

// ---------- fused prep: transpose + ELL build + bias pack in ONE dispatch ----------
// blocks [0, 8192)        : xT transpose (B,N) f32 -> (N,B) f16
// blocks [8192, 8704)     : fill_ell (ell pre-zeroed by memset)
// blocks [8704, 8768)     : pack gate constants
__global__ __launch_bounds__(256) void prep_kernel(
        const float* __restrict__ x, __half* __restrict__ xT,
        const int* __restrict__ w, const float* __restrict__ kern,
        int* __restrict__ counts, unsigned int* __restrict__ ell,
        uint2* __restrict__ ovf, int* __restrict__ ovf_cnt,
        const float* __restrict__ bi, const float* __restrict__ bf,
        const float* __restrict__ bo, const float* __restrict__ bg,
        float4* __restrict__ b4) {
    const int bid = blockIdx.x;
    const int t = threadIdx.x;
    if (bid < 8192) {
        // 32x32 transpose tile; threads as 32x8
        __shared__ float tile[32][33];
        int bx = (bid & 511) * 32;   // N offset
        int by = (bid >> 9) * 32;    // B offset
        int tx = t & 31, ty = t >> 5;
        #pragma unroll
        for (int i = 0; i < 32; i += 8)
            tile[ty + i][tx] = x[(size_t)(by + ty + i) * N + bx + tx];
        __syncthreads();
        #pragma unroll
        for (int i = 0; i < 32; i += 8)
            xT[(size_t)(bx + ty + i) * B + by + tx] = __float2half(tile[tx][ty + i]);
    } else if (bid < 8704) {
        int k = (bid - 8192) * 256 + t;
        int is64 = is64_(w);
        int row = is64 ? w[4 * k]     : w[2 * k];
        int col = is64 ? w[4 * k + 2] : w[2 * k + 1];
        unsigned int packed = (unsigned int)(unsigned short)row |
                              ((unsigned int)__half_as_ushort(__float2half_rn(kern[k])) << 16);
        int slot = atomicAdd(&counts[col], 1);
        if (slot < KMAX) {
            ell[col * KMAX + slot] = packed;
        } else {
            int pos = atomicAdd(ovf_cnt, 1);
            ovf[pos] = make_uint2((unsigned int)col, packed);
        }
    } else {
        // gate constants: (e^-bi, e^-bf, e^-bo, e^-2bg)
        // sigmoid(z+b) = 1/(1 + e^-b e^-z); tanh(z+bg) = 2/(1 + e^-2bg e^-2z) - 1
        int i = (bid - 8704) * 256 + t;
        b4[i] = make_float4(__expf(-bi[i]), __expf(-bf[i]), __expf(-bo[i]),
                            __expf(-2.f * bg[i]));
    }
}

// ---------- fused spmm + LSTM gates ----------
// Grid 4096 = (N/32) x 8. Block: 32 cols x 64 batch (one eighth).
//   q = blockIdx & 7 -> batch eighth; round-robin dispatch pins each q to one
//   XCD, whose L2 then only caches that eighth's 2 MB h-slice (fits in 4 MB
//   alongside ell + c traffic) -> gather L2-hits across dispatches.
// Thread: 1 col x 8 batch elems (uint4 = 8 f16). 8-lane col group gathers a
// contiguous 128 B row segment per entry; 16 entries -> two 8-deep ILP rounds.
// spmm accumulates in packed f16 (v_pk_fma_f16): 4 hfma2 per entry per lane,
// no per-entry cvts. ELL pads are zero (row 0, val 0) -> fma adds 0.
// LAST: writes transposed f32 directly to out via an LDS tile.
template <bool FIRST, bool LAST>
__global__ __launch_bounds__(256, 4) void lstm_iter_kernel(
        const uint4*  __restrict__ hin,     // (N, B/8) packed 8xf16
        uint4*        __restrict__ hout,    // (N, B/8)
        uint4*        __restrict__ c,       // (N, B/8) packed 8xf16
        float*        __restrict__ out,     // (B, N) f32 (LAST only)
        const int*    __restrict__ counts,  // N column degrees (overflow check)
        const uint4*  __restrict__ ell4,    // N*KMAX entries as uint4
        const uint2*  __restrict__ ovf,
        const int*    __restrict__ ovf_cnt,
        const float4* __restrict__ b4) {
    const int t     = threadIdx.x;
    const int lane8 = t & 7;
    const int sub   = t >> 3;                // col within block's 32
    const int q     = blockIdx.x & 7;        // batch eighth
    const int col   = (blockIdx.x >> 3) * 32 + sub;
    const int boff  = q * 8 + lane8;         // uint4 index within a row (B/8 = 64)

    // entry words (4 x 16B, uniform per 8-lane group)
    uint4 e0 = ell4[col * 4 + 0];
    uint4 e1 = ell4[col * 4 + 1];
    uint4 e2 = ell4[col * 4 + 2];
    uint4 e3 = ell4[col * 4 + 3];
    unsigned int en[KMAX] = { e0.x, e0.y, e0.z, e0.w, e1.x, e1.y, e1.z, e1.w,
                              e2.x, e2.y, e2.z, e2.w, e3.x, e3.y, e3.z, e3.w };

    // packed-f16 accumulators for 8 batch elems
    __half2 zp0 = __float2half2_rn(0.f), zp1 = zp0, zp2 = zp0, zp3 = zp0;
    #pragma unroll
    for (int half = 0; half < 2; ++half) {
        uint4 hv[8];
        #pragma unroll
        for (int j = 0; j < 8; ++j)
            hv[j] = hin[(en[half * 8 + j] & 0xFFFFu) * (B / 8) + boff];
        #pragma unroll
        for (int j = 0; j < 8; ++j) {
            __half  vh = __ushort_as_half((unsigned short)(en[half * 8 + j] >> 16));
            __half2 vv = __half2half2(vh);
            zp0 = __hfma2(vv, as_h2(hv[j].x), zp0);
            zp1 = __hfma2(vv, as_h2(hv[j].y), zp1);
            zp2 = __hfma2(vv, as_h2(hv[j].z), zp2);
            zp3 = __hfma2(vv, as_h2(hv[j].w), zp3);
        }
    }
    // rare overflow (deg > KMAX, ~0.3% of columns)
    int cnt = counts[col];
    if (cnt > KMAX) {
        int novf = *ovf_cnt;
        for (int k = 0; k < novf; ++k) {
            uint2 o = ovf[k];
            if (o.x == (unsigned int)col) {
                unsigned int p = o.y;
                __half2 vv = __half2half2(__ushort_as_half((unsigned short)(p >> 16)));
                uint4 hx = hin[(p & 0xFFFFu) * (B / 8) + boff];
                zp0 = __hfma2(vv, as_h2(hx.x), zp0);
                zp1 = __hfma2(vv, as_h2(hx.y), zp1);
                zp2 = __hfma2(vv, as_h2(hx.z), zp2);
                zp3 = __hfma2(vv, as_h2(hx.w), zp3);
            }
        }
    }

    // unpack z to f32 once
    float z[8];
    { float2 f;
      f = __half22float2(zp0); z[0] = f.x; z[1] = f.y;
      f = __half22float2(zp1); z[2] = f.x; z[3] = f.y;
      f = __half22float2(zp2); z[4] = f.x; z[5] = f.y;
      f = __half22float2(zp3); z[6] = f.x; z[7] = f.y; }

    const float4 bb = b4[col];               // (e^-bi, e^-bf, e^-bo, e^-2bg)
    const unsigned int idx = (unsigned int)col * (B / 8) + boff;

    float cv[8] = {0.f, 0.f, 0.f, 0.f, 0.f, 0.f, 0.f, 0.f};
    if (!FIRST) {
        uint4 cr = c[idx];
        float2 c0 = __half22float2(as_h2(cr.x));
        float2 c1 = __half22float2(as_h2(cr.y));
        float2 c2 = __half22float2(as_h2(cr.z));
        float2 c3 = __half22float2(as_h2(cr.w));
        cv[0] = c0.x; cv[1] = c0.y; cv[2] = c1.x; cv[3] = c1.y;
        cv[4] = c2.x; cv[5] = c2.y; cv[6] = c3.x; cv[7] = c3.y;
    }

    float hh[8], ch[8];
    #pragma unroll
    for (int e = 0; e < 8; ++e) {
        float ez = __expf(-z[e]);
        float ig = rcp_(fmaf(bb.x, ez, 1.f));
        float fg = rcp_(fmaf(bb.y, ez, 1.f));
        float og = rcp_(fmaf(bb.z, ez, 1.f));
        float dE = bb.w * ez * ez;
        float gg = fmaf(2.f, rcp_(1.f + dE), -1.f);   // tanh(z+bg)
        float cn = fg * cv[e] + ig * gg;
        ch[e] = cn;
        hh[e] = og * tanh_(cn);
    }

    if (!LAST) {
        c[idx]    = make_uint4(pack_h2(ch[0], ch[1]), pack_h2(ch[2], ch[3]),
                               pack_h2(ch[4], ch[5]), pack_h2(ch[6], ch[7]));
        hout[idx] = make_uint4(pack_h2(hh[0], hh[1]), pack_h2(hh[2], hh[3]),
                               pack_h2(hh[4], hh[5]), pack_h2(hh[6], hh[7]));
    } else {
        // transposed f32 write: block tile = 64 batch rows x 32 cols (+1 pad)
        __shared__ float tile[64 * 33];
        #pragma unroll
        for (int e = 0; e < 8; ++e)
            tile[(lane8 * 8 + e) * 33 + sub] = hh[e];
        __syncthreads();
        const int col0 = (blockIdx.x >> 3) * 32;
        #pragma unroll
        for (int k = 0; k < 8; ++k) {
            int i = k * 256 + t;
            int r = i >> 5;        // batch row 0..63
            int cc = i & 31;       // col 0..31
            out[(size_t)(q * 64 + r) * N + col0 + cc] = tile[r * 33 + cc];
        }
    }
}

extern "C" void kernel_launch(void* const* d_in, const int* in_sizes, int n_in,
                              void* d_out, int out_size, void* d_ws, size_t ws_size,
                              hipStream_t stream) {
    const float* x    = (const float*)d_in[0];
    const float* kern = (const float*)d_in[1];
    const float* b_i  = (const float*)d_in[2];
    const float* b_f  = (const float*)d_in[3];
    const float* b_o  = (const float*)d_in[4];
    const float* b_g  = (const float*)d_in[5];
    const int*   idxw = (const int*)d_in[6];

    char* ws = (char*)d_ws;
    uint4*        hA      = (uint4*)       (ws + 0);          // 16777216 B
    uint4*        hB      = (uint4*)       (ws + 16777216);   // 16777216 B
    uint4*        c       = (uint4*)       (ws + 33554432);   // 16777216 B
    unsigned int* ell     = (unsigned int*)(ws + 50331648);   // 1048576 B (zeroed)
    int*          counts  = (int*)         (ws + 51380224);   // 65536 B   (zeroed)
    int*          ovf_cnt = (int*)         (ws + 51445760);   // 4 B       (zeroed)
    uint2*        ovf     = (uint2*)       (ws + 51445768);   // 32768 B
    float4*       b4      = (float4*)      (ws + 51478656);   // 262144 B (16B-aligned)

    // one memset zeroes ell + counts + ovf_cnt (contiguous)
    hipMemsetAsync(ell, 0, 1048576 + 65536 + 4, stream);

    // fused prep: transpose (8192) + fill_ell (512) + pack_bias (64)
    prep_kernel<<<8768, 256, 0, stream>>>(x, (__half*)hA, idxw, kern,
                                          counts, ell, ovf, ovf_cnt,
                                          b_i, b_f, b_o, b_g, b4);

    const uint4* ell4 = (const uint4*)ell;
    float* out = (float*)d_out;
    const int GRID = (N / 32) * 8;   // 4096

    lstm_iter_kernel<true,  false><<<GRID, 256, 0, stream>>>(hA, hB, c, out, counts, ell4, ovf, ovf_cnt, b4);
    lstm_iter_kernel<false, false><<<GRID, 256, 0, stream>>>(hB, hA, c, out, counts, ell4, ovf, ovf_cnt, b4);
    lstm_iter_kernel<false, false><<<GRID, 256, 0, stream>>>(hA, hB, c, out, counts, ell4, ovf, ovf_cnt, b4);
    // LAST: writes transposed f32 directly into d_out (hout unused)
    lstm_iter_kernel<false, true ><<<GRID, 256, 0, stream>>>(hB, hA, c, out, counts, ell4, ovf, ovf_cnt, b4);
}